// Round 12
// baseline (274.829 us; speedup 1.0000x reference)
//
#include <hip/hip_runtime.h>

// Problem constants (match reference)
#define N_NODES 20000
#define N_EDGES 300000
#define DIM 256
#define NUM_RELS 8
#define NUM_BASES 4
#define NB 79               // (N_NODES + 255) / 256
#define K2 1280             // GEMM K: 4 basis blocks (1024) + x block (256)
#define TROW 1024           // T row length (4 * 256)
#define PREPX_BLOCKS 2500   // N_NODES * DIM / 8 / 256
#define CAP 96              // bucket capacity per node (mean degree 15)

typedef float f32x4 __attribute__((ext_vector_type(4)));
typedef short s16x8 __attribute__((ext_vector_type(8)));

__device__ __forceinline__ unsigned short f2bf(float f) {
    unsigned u = __builtin_bit_cast(unsigned, f);
    u += 0x7fffu + ((u >> 16) & 1u);          // round-to-nearest-even
    return (unsigned short)(u >> 16);
}
__device__ __forceinline__ float bf2f(unsigned short h) {
    unsigned u = ((unsigned)h) << 16;
    return __builtin_bit_cast(float, u);
}

__device__ __forceinline__ void gload_lds16(const void* g, void* l) {
    __builtin_amdgcn_global_load_lds((const __attribute__((address_space(1))) void*)g,
                                     (__attribute__((address_space(3))) void*)l,
                                     16, 0, 0);
}

// ---------------------------------------------------------------------------
// K1 (fused prep): blocks [0, 2500): x f32 -> bf16 (8 elems/thread)
//                  blocks [2500, 2756): W2[o][k] bf16
//                  blocks [2756, 2835): cnt zero
// ---------------------------------------------------------------------------
__global__ __launch_bounds__(256) void prep_all(const float* __restrict__ x,
                                                const float* __restrict__ basis,
                                                const float* __restrict__ loopw,
                                                unsigned short* __restrict__ xb,
                                                unsigned short* __restrict__ W2,
                                                int* __restrict__ cnt) {
    int blk = blockIdx.x;
    if (blk < PREPX_BLOCKS) {
        int idx = (blk * 256 + threadIdx.x) * 8;
        float4 v0 = *reinterpret_cast<const float4*>(x + idx);
        float4 v1 = *reinterpret_cast<const float4*>(x + idx + 4);
        s16x8 o;
        o[0] = (short)f2bf(v0.x); o[1] = (short)f2bf(v0.y);
        o[2] = (short)f2bf(v0.z); o[3] = (short)f2bf(v0.w);
        o[4] = (short)f2bf(v1.x); o[5] = (short)f2bf(v1.y);
        o[6] = (short)f2bf(v1.z); o[7] = (short)f2bf(v1.w);
        *reinterpret_cast<s16x8*>(xb + idx) = o;
    } else if (blk < PREPX_BLOCKS + DIM) {
        int o = blk - PREPX_BLOCKS;   // 0..255
        int i = threadIdx.x;          // 0..255
#pragma unroll
        for (int b = 0; b < NUM_BASES; ++b)
            W2[(size_t)o * K2 + b * 256 + i] = f2bf(basis[((size_t)b * 256 + i) * 256 + o]);
        W2[(size_t)o * K2 + 1024 + i] = f2bf(loopw[(size_t)i * 256 + o]);
    } else {
        int i = (blk - PREPX_BLOCKS - DIM) * 256 + threadIdx.x;
        if (i < N_NODES) cnt[i] = 0;
    }
}

// ---------------------------------------------------------------------------
// K2: direct bucketing — no histogram, no scan.
// ---------------------------------------------------------------------------
__global__ __launch_bounds__(256) void bucket_fill(const int* __restrict__ src,
                                                   const int* __restrict__ dst,
                                                   const int* __restrict__ et,
                                                   int* __restrict__ cnt,
                                                   int* __restrict__ bucket) {
    int e = blockIdx.x * 256 + threadIdx.x;
    if (e >= N_EDGES) return;
    int d = dst[e];
    int pos = atomicAdd(&cnt[d], 1);
    if (pos < CAP)
        bucket[(size_t)d * CAP + pos] = src[e] * NUM_RELS + et[e];
}

// ---------------------------------------------------------------------------
// K3: gather. Per-relation register sums (no per-edge comp multiply):
//   u[r][j] += x[src_e][j]   (switch on wave-uniform relation, 8 VALU/edge)
// then fold T[b] = sum_r comp[r][b] * u[r] once per node.
// One wave per node, 4 edges' row-loads in flight.
// ---------------------------------------------------------------------------
#define ACCUM(p, v)                                                       \
    {                                                                     \
        float x0 = bf2f((v).x), x1 = bf2f((v).y),                         \
              x2 = bf2f((v).z), x3 = bf2f((v).w);                         \
        switch ((p) & 7) {                                                \
        case 0: u[0][0]+=x0; u[0][1]+=x1; u[0][2]+=x2; u[0][3]+=x3; break;\
        case 1: u[1][0]+=x0; u[1][1]+=x1; u[1][2]+=x2; u[1][3]+=x3; break;\
        case 2: u[2][0]+=x0; u[2][1]+=x1; u[2][2]+=x2; u[2][3]+=x3; break;\
        case 3: u[3][0]+=x0; u[3][1]+=x1; u[3][2]+=x2; u[3][3]+=x3; break;\
        case 4: u[4][0]+=x0; u[4][1]+=x1; u[4][2]+=x2; u[4][3]+=x3; break;\
        case 5: u[5][0]+=x0; u[5][1]+=x1; u[5][2]+=x2; u[5][3]+=x3; break;\
        case 6: u[6][0]+=x0; u[6][1]+=x1; u[6][2]+=x2; u[6][3]+=x3; break;\
        default:u[7][0]+=x0; u[7][1]+=x1; u[7][2]+=x2; u[7][3]+=x3; break;\
        }                                                                 \
    }

__global__ __launch_bounds__(256) void gather_T(const int* __restrict__ cnt,
                                                const int* __restrict__ bucket,
                                                const unsigned short* __restrict__ Xb,
                                                const float* __restrict__ comp,
                                                unsigned short* __restrict__ T) {
    int n = blockIdx.x * 4 + (threadIdx.x >> 6);   // grid exact: 5000 blocks
    int lane = threadIdx.x & 63;
    int c = lane * 4;

    float u[NUM_RELS][4] = {};                     // per-relation sums (32 VGPR)
    int deg = cnt[n]; if (deg > CAP) deg = CAP;
    const int base = n * CAP;

    int e = 0;
    for (; e + 3 < deg; e += 4) {
        int p0 = bucket[base + e];
        int p1 = bucket[base + e + 1];
        int p2 = bucket[base + e + 2];
        int p3 = bucket[base + e + 3];
        // hoist all 4 row loads (4 outstanding 512B gathers per wave)
        ushort4 v0 = *reinterpret_cast<const ushort4*>(Xb + (size_t)(p0 >> 3) * DIM + c);
        ushort4 v1 = *reinterpret_cast<const ushort4*>(Xb + (size_t)(p1 >> 3) * DIM + c);
        ushort4 v2 = *reinterpret_cast<const ushort4*>(Xb + (size_t)(p2 >> 3) * DIM + c);
        ushort4 v3 = *reinterpret_cast<const ushort4*>(Xb + (size_t)(p3 >> 3) * DIM + c);
        ACCUM(p0, v0);
        ACCUM(p1, v1);
        ACCUM(p2, v2);
        ACCUM(p3, v3);
    }
    for (; e < deg; ++e) {
        int p = bucket[base + e];
        ushort4 v = *reinterpret_cast<const ushort4*>(Xb + (size_t)(p >> 3) * DIM + c);
        ACCUM(p, v);
    }

    // fold with comp and write T: T[n, b*256 + c..c+3]
#pragma unroll
    for (int b = 0; b < NUM_BASES; ++b) {
        float t0 = 0.f, t1 = 0.f, t2 = 0.f, t3 = 0.f;
#pragma unroll
        for (int r = 0; r < NUM_RELS; ++r) {
            float cw = comp[r * NUM_BASES + b];
            t0 += cw * u[r][0];
            t1 += cw * u[r][1];
            t2 += cw * u[r][2];
            t3 += cw * u[r][3];
        }
        ushort4 o;
        o.x = f2bf(t0); o.y = f2bf(t1); o.z = f2bf(t2); o.w = f2bf(t3);
        *reinterpret_cast<ushort4*>(T + (size_t)n * TROW + b * 256 + c) = o;
    }
}

// ---------------------------------------------------------------------------
// K4: out[m, o] = sum_k A[m, k] * W2[o, k] + bias[o]
//   A = [T | x_bf16] (K=1280, source switch at k=1024).
// 64x256 tile, BK=64, 512 threads (8 waves, wave = 32x64), grid 313,
// global_load_lds + XOR swizzle, 2-phase double-buffered LDS.
// ---------------------------------------------------------------------------
#define BM 64
#define BN 256
#define BK 64
#define NT 20   // K2 / BK

__global__ __launch_bounds__(512) void gemm_out(const unsigned short* __restrict__ Tb,
                                                const unsigned short* __restrict__ Xb,
                                                const unsigned short* __restrict__ W2,
                                                const float* __restrict__ bias,
                                                float* __restrict__ out) {
    __shared__ unsigned short At[2][BM * BK];   // 2 x 8KB
    __shared__ unsigned short Bt[2][BN * BK];   // 2 x 32KB
    const int m0 = blockIdx.x * BM;
    const int t = threadIdx.x;
    const int lane = t & 63;
    const int w = t >> 6;            // 0..7
    const int wr = w >> 2;           // 0..1  (32-row half)
    const int wc = w & 3;            // 0..3  (64-col block)
    const int srow = lane >> 3;      // 0..7
    const int sgrp = lane & 7;       // 0..7

    f32x4 acc[2][4] = {};

    auto stage = [&](int kt, int b) {
        int k0 = kt * BK;
        const unsigned short* As; int astr, ac0;
        if (k0 < TROW) { As = Tb; astr = TROW; ac0 = k0; }
        else           { As = Xb; astr = DIM;  ac0 = k0 - TROW; }
        int scol = (sgrp ^ srow) << 3;
        {   // A: 64 rows, 1 load/thread
            int rt = w * 8 + srow;
            int gr = m0 + rt; if (gr > N_NODES - 1) gr = N_NODES - 1;
            gload_lds16(As + (size_t)gr * astr + ac0 + scol, &At[b][(w * 8) * BK]);
        }
#pragma unroll
        for (int is = 0; is < 4; ++is) {   // B: 256 rows, 4 loads/thread
            int rt = w * 32 + is * 8 + srow;
            gload_lds16(W2 + (size_t)rt * K2 + k0 + scol, &Bt[b][(w * 32 + is * 8) * BK]);
        }
    };

    stage(0, 0);
    __syncthreads();    // drains vmcnt(0)

    for (int kt = 0; kt < NT; ++kt) {
        int cb = kt & 1;
        if (kt + 1 < NT) stage(kt + 1, cb ^ 1);   // prefetch overlaps compute below
#pragma unroll
        for (int kk = 0; kk < BK; kk += 32) {
            const int gg = (kk >> 3) + (lane >> 4);
            s16x8 af[2], bfr[4];
#pragma unroll
            for (int m = 0; m < 2; ++m) {
                int r = wr * 32 + m * 16 + (lane & 15);
                af[m] = *reinterpret_cast<const s16x8*>(&At[cb][r * BK + ((gg ^ (r & 7)) << 3)]);
            }
#pragma unroll
            for (int n = 0; n < 4; ++n) {
                int r = wc * 64 + n * 16 + (lane & 15);
                bfr[n] = *reinterpret_cast<const s16x8*>(&Bt[cb][r * BK + ((gg ^ (r & 7)) << 3)]);
            }
#pragma unroll
            for (int m = 0; m < 2; ++m)
#pragma unroll
                for (int n = 0; n < 4; ++n)
                    acc[m][n] = __builtin_amdgcn_mfma_f32_16x16x32_bf16(af[m], bfr[n], acc[m][n], 0, 0, 0);
        }
        __syncthreads();   // drains prefetch vmcnt + lds reads; buffers swap safely
    }

    // epilogue: out = acc + bias (f32 direct)
    float b4[4];
#pragma unroll
    for (int n = 0; n < 4; ++n) b4[n] = bias[wc * 64 + n * 16 + (lane & 15)];
#pragma unroll
    for (int m = 0; m < 2; ++m) {
        int rbase = m0 + wr * 32 + m * 16 + ((lane >> 4) * 4);
#pragma unroll
        for (int j = 0; j < 4; ++j) {
            int row = rbase + j;
            if (row < N_NODES) {
#pragma unroll
                for (int n = 0; n < 4; ++n) {
                    int col = wc * 64 + n * 16 + (lane & 15);
                    out[(size_t)row * DIM + col] = acc[m][n][j] + b4[n];
                }
            }
        }
    }
}

// ---------------------------------------------------------------------------
extern "C" void kernel_launch(void* const* d_in, const int* in_sizes, int n_in,
                              void* d_out, int out_size, void* d_ws, size_t ws_size,
                              hipStream_t stream) {
    const float* x      = (const float*)d_in[0];
    const int*   src    = (const int*)d_in[1];
    const int*   dst    = (const int*)d_in[2];
    const int*   etypes = (const int*)d_in[3];
    const float* basis  = (const float*)d_in[4];
    const float* comp   = (const float*)d_in[5];
    const float* loopw  = (const float*)d_in[6];
    const float* bias   = (const float*)d_in[7];
    float* out = (float*)d_out;

    char* p = (char*)d_ws;
    unsigned short* W2 = (unsigned short*)p;            p += (size_t)DIM * K2 * 2;          // 0.66 MB
    unsigned short* Xb = (unsigned short*)p;            p += (size_t)N_NODES * DIM * 2;     // 10.24 MB
    unsigned short* T  = (unsigned short*)p;            p += (size_t)N_NODES * TROW * 2;    // 40.96 MB
    int* cnt    = (int*)p;                              p += (size_t)N_NODES * 4;           // 80 KB
    int* bucket = (int*)p;                              p += (size_t)N_NODES * CAP * 4;     // 7.68 MB

    prep_all<<<PREPX_BLOCKS + DIM + NB, 256, 0, stream>>>(x, basis, loopw, Xb, W2, cnt);

    bucket_fill<<<(N_EDGES + 255) / 256, 256, 0, stream>>>(src, dst, etypes, cnt, bucket);

    gather_T<<<N_NODES / 4, 256, 0, stream>>>(cnt, bucket, Xb, comp, T);

    gemm_out<<<(N_NODES + BM - 1) / BM, 512, 0, stream>>>(T, Xb, W2, bias, out);
}

// Round 13
// 97.963 us; speedup vs baseline: 2.8054x; 2.8054x over previous
//
#include <hip/hip_runtime.h>

// Problem constants (match reference)
#define N_NODES 20000
#define N_EDGES 300000
#define DIM 256
#define NUM_RELS 8
#define NUM_BASES 4
#define K2 1280             // GEMM K: 4 basis blocks (1024) + x block (256)
#define TROW 1024           // T row length (4 * 256)
#define PREPX_BLOCKS 2500   // N_NODES * DIM / 8 / 256
#define CAP_R 20            // per-(node,relation) bucket capacity (lambda~1.9)
#define ZB 625              // blocks to zero cnt8: 160000 / 256

typedef float f32x4 __attribute__((ext_vector_type(4)));
typedef short s16x8 __attribute__((ext_vector_type(8)));

__device__ __forceinline__ unsigned short f2bf(float f) {
    unsigned u = __builtin_bit_cast(unsigned, f);
    u += 0x7fffu + ((u >> 16) & 1u);          // round-to-nearest-even
    return (unsigned short)(u >> 16);
}
__device__ __forceinline__ float bf2f(unsigned short h) {
    unsigned u = ((unsigned)h) << 16;
    return __builtin_bit_cast(float, u);
}

__device__ __forceinline__ void gload_lds16(const void* g, void* l) {
    __builtin_amdgcn_global_load_lds((const __attribute__((address_space(1))) void*)g,
                                     (__attribute__((address_space(3))) void*)l,
                                     16, 0, 0);
}

// ---------------------------------------------------------------------------
// K1 (fused prep): blocks [0, 2500): x f32 -> bf16 (8 elems/thread)
//                  blocks [2500, 2756): W2[o][k] bf16
//                  blocks [2756, 3381): cnt8 zero (160000 ints)
// ---------------------------------------------------------------------------
__global__ __launch_bounds__(256) void prep_all(const float* __restrict__ x,
                                                const float* __restrict__ basis,
                                                const float* __restrict__ loopw,
                                                unsigned short* __restrict__ xb,
                                                unsigned short* __restrict__ W2,
                                                int* __restrict__ cnt8) {
    int blk = blockIdx.x;
    if (blk < PREPX_BLOCKS) {
        int idx = (blk * 256 + threadIdx.x) * 8;
        float4 v0 = *reinterpret_cast<const float4*>(x + idx);
        float4 v1 = *reinterpret_cast<const float4*>(x + idx + 4);
        s16x8 o;
        o[0] = (short)f2bf(v0.x); o[1] = (short)f2bf(v0.y);
        o[2] = (short)f2bf(v0.z); o[3] = (short)f2bf(v0.w);
        o[4] = (short)f2bf(v1.x); o[5] = (short)f2bf(v1.y);
        o[6] = (short)f2bf(v1.z); o[7] = (short)f2bf(v1.w);
        *reinterpret_cast<s16x8*>(xb + idx) = o;
    } else if (blk < PREPX_BLOCKS + DIM) {
        int o = blk - PREPX_BLOCKS;   // 0..255
        int i = threadIdx.x;          // 0..255
#pragma unroll
        for (int b = 0; b < NUM_BASES; ++b)
            W2[(size_t)o * K2 + b * 256 + i] = f2bf(basis[((size_t)b * 256 + i) * 256 + o]);
        W2[(size_t)o * K2 + 1024 + i] = f2bf(loopw[(size_t)i * 256 + o]);
    } else {
        int i = (blk - PREPX_BLOCKS - DIM) * 256 + threadIdx.x;
        if (i < N_NODES * NUM_RELS) cnt8[i] = 0;
    }
}

// ---------------------------------------------------------------------------
// K2: per-(node,relation) bucketing — edges pre-sorted by relation.
// ---------------------------------------------------------------------------
__global__ __launch_bounds__(256) void bucket_fill(const int* __restrict__ src,
                                                   const int* __restrict__ dst,
                                                   const int* __restrict__ et,
                                                   int* __restrict__ cnt8,
                                                   int* __restrict__ bucket) {
    int e = blockIdx.x * 256 + threadIdx.x;
    if (e >= N_EDGES) return;
    int cell = dst[e] * NUM_RELS + et[e];
    int pos = atomicAdd(&cnt8[cell], 1);
    if (pos < CAP_R)
        bucket[(size_t)cell * CAP_R + pos] = src[e];
}

// ---------------------------------------------------------------------------
// K3: gather. Edges are relation-sorted, so the inner loop is PURE ADDS
// (4 cvt + 4 fadd per edge, no comp multiply, no branch); comp fold happens
// once per non-empty relation. One wave per node, 4 row-loads in flight.
// ---------------------------------------------------------------------------
__global__ __launch_bounds__(256) void gather_T(const int* __restrict__ cnt8,
                                                const int* __restrict__ bucket,
                                                const unsigned short* __restrict__ Xb,
                                                const float* __restrict__ comp,
                                                unsigned short* __restrict__ T) {
    int n = blockIdx.x * 4 + (threadIdx.x >> 6);   // grid exact: 5000 blocks
    int lane = threadIdx.x & 63;
    int c = lane * 4;

    float acc[NUM_BASES][4] = {};

#pragma unroll
    for (int r = 0; r < NUM_RELS; ++r) {
        int cell = n * NUM_RELS + r;
        int k = cnt8[cell]; if (k > CAP_R) k = CAP_R;
        if (k == 0) continue;                      // wave-uniform skip
        const int base = cell * CAP_R;
        float s0 = 0.f, s1 = 0.f, s2 = 0.f, s3 = 0.f;
        int e = 0;
        for (; e + 3 < k; e += 4) {
            int q0 = bucket[base + e];
            int q1 = bucket[base + e + 1];
            int q2 = bucket[base + e + 2];
            int q3 = bucket[base + e + 3];
            ushort4 v0 = *reinterpret_cast<const ushort4*>(Xb + (size_t)q0 * DIM + c);
            ushort4 v1 = *reinterpret_cast<const ushort4*>(Xb + (size_t)q1 * DIM + c);
            ushort4 v2 = *reinterpret_cast<const ushort4*>(Xb + (size_t)q2 * DIM + c);
            ushort4 v3 = *reinterpret_cast<const ushort4*>(Xb + (size_t)q3 * DIM + c);
            s0 += (bf2f(v0.x) + bf2f(v1.x)) + (bf2f(v2.x) + bf2f(v3.x));
            s1 += (bf2f(v0.y) + bf2f(v1.y)) + (bf2f(v2.y) + bf2f(v3.y));
            s2 += (bf2f(v0.z) + bf2f(v1.z)) + (bf2f(v2.z) + bf2f(v3.z));
            s3 += (bf2f(v0.w) + bf2f(v1.w)) + (bf2f(v2.w) + bf2f(v3.w));
        }
        for (; e < k; ++e) {
            int q = bucket[base + e];
            ushort4 v = *reinterpret_cast<const ushort4*>(Xb + (size_t)q * DIM + c);
            s0 += bf2f(v.x); s1 += bf2f(v.y); s2 += bf2f(v.z); s3 += bf2f(v.w);
        }
        // fold this relation into the 4 basis accumulators
#pragma unroll
        for (int b = 0; b < NUM_BASES; ++b) {
            float cw = comp[r * NUM_BASES + b];
            acc[b][0] += cw * s0;
            acc[b][1] += cw * s1;
            acc[b][2] += cw * s2;
            acc[b][3] += cw * s3;
        }
    }

#pragma unroll
    for (int b = 0; b < NUM_BASES; ++b) {
        ushort4 o;
        o.x = f2bf(acc[b][0]); o.y = f2bf(acc[b][1]);
        o.z = f2bf(acc[b][2]); o.w = f2bf(acc[b][3]);
        *reinterpret_cast<ushort4*>(T + (size_t)n * TROW + b * 256 + c) = o;
    }
}

// ---------------------------------------------------------------------------
// K4: out[m, o] = sum_k A[m, k] * W2[o, k] + bias[o]
//   A = [T | x_bf16] (K=1280, source switch at k=1024).
// 64x256 tile, BK=64, 512 threads (8 waves, wave = 32x64), grid 313,
// global_load_lds + XOR swizzle, 2-phase double-buffered LDS.
// ---------------------------------------------------------------------------
#define BM 64
#define BN 256
#define BK 64
#define NT 20   // K2 / BK

__global__ __launch_bounds__(512) void gemm_out(const unsigned short* __restrict__ Tb,
                                                const unsigned short* __restrict__ Xb,
                                                const unsigned short* __restrict__ W2,
                                                const float* __restrict__ bias,
                                                float* __restrict__ out) {
    __shared__ unsigned short At[2][BM * BK];   // 2 x 8KB
    __shared__ unsigned short Bt[2][BN * BK];   // 2 x 32KB
    const int m0 = blockIdx.x * BM;
    const int t = threadIdx.x;
    const int lane = t & 63;
    const int w = t >> 6;            // 0..7
    const int wr = w >> 2;           // 0..1  (32-row half)
    const int wc = w & 3;            // 0..3  (64-col block)
    const int srow = lane >> 3;      // 0..7
    const int sgrp = lane & 7;       // 0..7

    f32x4 acc[2][4] = {};

    auto stage = [&](int kt, int b) {
        int k0 = kt * BK;
        const unsigned short* As; int astr, ac0;
        if (k0 < TROW) { As = Tb; astr = TROW; ac0 = k0; }
        else           { As = Xb; astr = DIM;  ac0 = k0 - TROW; }
        int scol = (sgrp ^ srow) << 3;
        {   // A: 64 rows, 1 load/thread
            int rt = w * 8 + srow;
            int gr = m0 + rt; if (gr > N_NODES - 1) gr = N_NODES - 1;
            gload_lds16(As + (size_t)gr * astr + ac0 + scol, &At[b][(w * 8) * BK]);
        }
#pragma unroll
        for (int is = 0; is < 4; ++is) {   // B: 256 rows, 4 loads/thread
            int rt = w * 32 + is * 8 + srow;
            gload_lds16(W2 + (size_t)rt * K2 + k0 + scol, &Bt[b][(w * 32 + is * 8) * BK]);
        }
    };

    stage(0, 0);
    __syncthreads();    // drains vmcnt(0)

    for (int kt = 0; kt < NT; ++kt) {
        int cb = kt & 1;
        if (kt + 1 < NT) stage(kt + 1, cb ^ 1);   // prefetch overlaps compute below
#pragma unroll
        for (int kk = 0; kk < BK; kk += 32) {
            const int gg = (kk >> 3) + (lane >> 4);
            s16x8 af[2], bfr[4];
#pragma unroll
            for (int m = 0; m < 2; ++m) {
                int r = wr * 32 + m * 16 + (lane & 15);
                af[m] = *reinterpret_cast<const s16x8*>(&At[cb][r * BK + ((gg ^ (r & 7)) << 3)]);
            }
#pragma unroll
            for (int n = 0; n < 4; ++n) {
                int r = wc * 64 + n * 16 + (lane & 15);
                bfr[n] = *reinterpret_cast<const s16x8*>(&Bt[cb][r * BK + ((gg ^ (r & 7)) << 3)]);
            }
#pragma unroll
            for (int m = 0; m < 2; ++m)
#pragma unroll
                for (int n = 0; n < 4; ++n)
                    acc[m][n] = __builtin_amdgcn_mfma_f32_16x16x32_bf16(af[m], bfr[n], acc[m][n], 0, 0, 0);
        }
        __syncthreads();   // drains prefetch vmcnt + lds reads; buffers swap safely
    }

    // epilogue: out = acc + bias (f32 direct)
    float b4[4];
#pragma unroll
    for (int n = 0; n < 4; ++n) b4[n] = bias[wc * 64 + n * 16 + (lane & 15)];
#pragma unroll
    for (int m = 0; m < 2; ++m) {
        int rbase = m0 + wr * 32 + m * 16 + ((lane >> 4) * 4);
#pragma unroll
        for (int j = 0; j < 4; ++j) {
            int row = rbase + j;
            if (row < N_NODES) {
#pragma unroll
                for (int n = 0; n < 4; ++n) {
                    int col = wc * 64 + n * 16 + (lane & 15);
                    out[(size_t)row * DIM + col] = acc[m][n][j] + b4[n];
                }
            }
        }
    }
}

// ---------------------------------------------------------------------------
extern "C" void kernel_launch(void* const* d_in, const int* in_sizes, int n_in,
                              void* d_out, int out_size, void* d_ws, size_t ws_size,
                              hipStream_t stream) {
    const float* x      = (const float*)d_in[0];
    const int*   src    = (const int*)d_in[1];
    const int*   dst    = (const int*)d_in[2];
    const int*   etypes = (const int*)d_in[3];
    const float* basis  = (const float*)d_in[4];
    const float* comp   = (const float*)d_in[5];
    const float* loopw  = (const float*)d_in[6];
    const float* bias   = (const float*)d_in[7];
    float* out = (float*)d_out;

    char* p = (char*)d_ws;
    unsigned short* W2 = (unsigned short*)p;            p += (size_t)DIM * K2 * 2;          // 0.66 MB
    unsigned short* Xb = (unsigned short*)p;            p += (size_t)N_NODES * DIM * 2;     // 10.24 MB
    unsigned short* T  = (unsigned short*)p;            p += (size_t)N_NODES * TROW * 2;    // 40.96 MB
    int* cnt8   = (int*)p;                              p += (size_t)N_NODES * NUM_RELS * 4;        // 0.64 MB
    int* bucket = (int*)p;                              p += (size_t)N_NODES * NUM_RELS * CAP_R * 4; // 12.8 MB

    prep_all<<<PREPX_BLOCKS + DIM + ZB, 256, 0, stream>>>(x, basis, loopw, Xb, W2, cnt8);

    bucket_fill<<<(N_EDGES + 255) / 256, 256, 0, stream>>>(src, dst, etypes, cnt8, bucket);

    gather_T<<<N_NODES / 4, 256, 0, stream>>>(cnt8, bucket, Xb, comp, T);

    gemm_out<<<(N_NODES + BM - 1) / BM, 512, 0, stream>>>(T, Xb, W2, bias, out);
}

// Round 14
// 88.028 us; speedup vs baseline: 3.1221x; 1.1129x over previous
//
#include <hip/hip_runtime.h>

// Problem constants (match reference)
#define N_NODES 20000
#define N_EDGES 300000
#define DIM 256
#define NUM_RELS 8
#define NUM_BASES 4
#define NB 79               // (N_NODES + 255) / 256
#define K2 1280             // GEMM K: 4 basis blocks (1024) + x block (256)
#define TROW 1024           // T row length (4 * 256)
#define PREPX_BLOCKS 2500   // N_NODES * DIM / 8 / 256
#define CAP 96              // flat bucket capacity per node (mean degree 15)

typedef float f32x4 __attribute__((ext_vector_type(4)));
typedef short s16x8 __attribute__((ext_vector_type(8)));

__device__ __forceinline__ unsigned short f2bf(float f) {
    unsigned u = __builtin_bit_cast(unsigned, f);
    u += 0x7fffu + ((u >> 16) & 1u);          // round-to-nearest-even
    return (unsigned short)(u >> 16);
}
__device__ __forceinline__ float bf2f(unsigned short h) {
    unsigned u = ((unsigned)h) << 16;
    return __builtin_bit_cast(float, u);
}

__device__ __forceinline__ void gload_lds16(const void* g, void* l) {
    __builtin_amdgcn_global_load_lds((const __attribute__((address_space(1))) void*)g,
                                     (__attribute__((address_space(3))) void*)l,
                                     16, 0, 0);
}

// ---------------------------------------------------------------------------
// K1 (fused prep): blocks [0, 2500): x f32 -> bf16 (8 elems/thread)
//                  blocks [2500, 2756): W2[o][k] bf16
//                  blocks [2756, 2835): cnt zero
// ---------------------------------------------------------------------------
__global__ __launch_bounds__(256) void prep_all(const float* __restrict__ x,
                                                const float* __restrict__ basis,
                                                const float* __restrict__ loopw,
                                                unsigned short* __restrict__ xb,
                                                unsigned short* __restrict__ W2,
                                                int* __restrict__ cnt) {
    int blk = blockIdx.x;
    if (blk < PREPX_BLOCKS) {
        int idx = (blk * 256 + threadIdx.x) * 8;
        float4 v0 = *reinterpret_cast<const float4*>(x + idx);
        float4 v1 = *reinterpret_cast<const float4*>(x + idx + 4);
        s16x8 o;
        o[0] = (short)f2bf(v0.x); o[1] = (short)f2bf(v0.y);
        o[2] = (short)f2bf(v0.z); o[3] = (short)f2bf(v0.w);
        o[4] = (short)f2bf(v1.x); o[5] = (short)f2bf(v1.y);
        o[6] = (short)f2bf(v1.z); o[7] = (short)f2bf(v1.w);
        *reinterpret_cast<s16x8*>(xb + idx) = o;
    } else if (blk < PREPX_BLOCKS + DIM) {
        int o = blk - PREPX_BLOCKS;   // 0..255
        int i = threadIdx.x;          // 0..255
#pragma unroll
        for (int b = 0; b < NUM_BASES; ++b)
            W2[(size_t)o * K2 + b * 256 + i] = f2bf(basis[((size_t)b * 256 + i) * 256 + o]);
        W2[(size_t)o * K2 + 1024 + i] = f2bf(loopw[(size_t)i * 256 + o]);
    } else {
        int i = (blk - PREPX_BLOCKS - DIM) * 256 + threadIdx.x;
        if (i < N_NODES) cnt[i] = 0;
    }
}

// ---------------------------------------------------------------------------
// K2: flat per-node bucketing.
// ---------------------------------------------------------------------------
__global__ __launch_bounds__(256) void bucket_fill(const int* __restrict__ src,
                                                   const int* __restrict__ dst,
                                                   const int* __restrict__ et,
                                                   int* __restrict__ cnt,
                                                   int* __restrict__ bucket) {
    int e = blockIdx.x * 256 + threadIdx.x;
    if (e >= N_EDGES) return;
    int d = dst[e];
    int pos = atomicAdd(&cnt[d], 1);
    if (pos < CAP)
        bucket[(size_t)d * CAP + pos] = src[e] * NUM_RELS + et[e];
}

// ---------------------------------------------------------------------------
// K3: gather: T[d, b*256+j] = sum_{e->d} comp[et_e, b] * x_bf16[src_e, j]
// One wave per node. 8 edges in flight (8 independent row + comp loads),
// all register arrays fully unrolled (static indices).
// ---------------------------------------------------------------------------
__device__ __forceinline__ void edge_fma(float acc[NUM_BASES][4],
                                         ushort4 v, float4 cw) {
    float x0 = bf2f(v.x), x1 = bf2f(v.y), x2 = bf2f(v.z), x3 = bf2f(v.w);
    acc[0][0] += cw.x * x0; acc[0][1] += cw.x * x1; acc[0][2] += cw.x * x2; acc[0][3] += cw.x * x3;
    acc[1][0] += cw.y * x0; acc[1][1] += cw.y * x1; acc[1][2] += cw.y * x2; acc[1][3] += cw.y * x3;
    acc[2][0] += cw.z * x0; acc[2][1] += cw.z * x1; acc[2][2] += cw.z * x2; acc[2][3] += cw.z * x3;
    acc[3][0] += cw.w * x0; acc[3][1] += cw.w * x1; acc[3][2] += cw.w * x2; acc[3][3] += cw.w * x3;
}

__global__ __launch_bounds__(256) void gather_T(const int* __restrict__ cnt,
                                                const int* __restrict__ bucket,
                                                const unsigned short* __restrict__ Xb,
                                                const float* __restrict__ comp,
                                                unsigned short* __restrict__ T) {
    int n = blockIdx.x * 4 + (threadIdx.x >> 6);   // grid exact: 5000 blocks
    int lane = threadIdx.x & 63;
    int c = lane * 4;

    float acc[NUM_BASES][4] = {};
    int deg = cnt[n]; if (deg > CAP) deg = CAP;
    const int base = n * CAP;

    int e = 0;
    // 8 edges in flight
    for (; e + 7 < deg; e += 8) {
        int p[8];
#pragma unroll
        for (int i = 0; i < 8; ++i) p[i] = bucket[base + e + i];
        ushort4 v[8];
#pragma unroll
        for (int i = 0; i < 8; ++i)
            v[i] = *reinterpret_cast<const ushort4*>(Xb + (size_t)(p[i] >> 3) * DIM + c);
        float4 cw[8];
#pragma unroll
        for (int i = 0; i < 8; ++i)
            cw[i] = *reinterpret_cast<const float4*>(comp + (p[i] & 7) * 4);
#pragma unroll
        for (int i = 0; i < 8; ++i)
            edge_fma(acc, v[i], cw[i]);
    }
    // 4 edges in flight
    for (; e + 3 < deg; e += 4) {
        int p[4];
#pragma unroll
        for (int i = 0; i < 4; ++i) p[i] = bucket[base + e + i];
        ushort4 v[4];
#pragma unroll
        for (int i = 0; i < 4; ++i)
            v[i] = *reinterpret_cast<const ushort4*>(Xb + (size_t)(p[i] >> 3) * DIM + c);
        float4 cw[4];
#pragma unroll
        for (int i = 0; i < 4; ++i)
            cw[i] = *reinterpret_cast<const float4*>(comp + (p[i] & 7) * 4);
#pragma unroll
        for (int i = 0; i < 4; ++i)
            edge_fma(acc, v[i], cw[i]);
    }
    // singles (<= 3)
    for (; e < deg; ++e) {
        int p = bucket[base + e];
        ushort4 v = *reinterpret_cast<const ushort4*>(Xb + (size_t)(p >> 3) * DIM + c);
        float4 cw = *reinterpret_cast<const float4*>(comp + (p & 7) * 4);
        edge_fma(acc, v, cw);
    }

#pragma unroll
    for (int b = 0; b < NUM_BASES; ++b) {
        ushort4 o;
        o.x = f2bf(acc[b][0]); o.y = f2bf(acc[b][1]);
        o.z = f2bf(acc[b][2]); o.w = f2bf(acc[b][3]);
        *reinterpret_cast<ushort4*>(T + (size_t)n * TROW + b * 256 + c) = o;
    }
}

// ---------------------------------------------------------------------------
// K4: out[m, o] = sum_k A[m, k] * W2[o, k] + bias[o]
//   A = [T | x_bf16] (K=1280, source switch at k=1024).
// 64x256 tile, BK=64, 512 threads (8 waves, wave = 32x64), grid 313,
// global_load_lds + XOR swizzle, 2-phase double-buffered LDS.
// ---------------------------------------------------------------------------
#define BM 64
#define BN 256
#define BK 64
#define NT 20   // K2 / BK

__global__ __launch_bounds__(512) void gemm_out(const unsigned short* __restrict__ Tb,
                                                const unsigned short* __restrict__ Xb,
                                                const unsigned short* __restrict__ W2,
                                                const float* __restrict__ bias,
                                                float* __restrict__ out) {
    __shared__ unsigned short At[2][BM * BK];   // 2 x 8KB
    __shared__ unsigned short Bt[2][BN * BK];   // 2 x 32KB
    const int m0 = blockIdx.x * BM;
    const int t = threadIdx.x;
    const int lane = t & 63;
    const int w = t >> 6;            // 0..7
    const int wr = w >> 2;           // 0..1  (32-row half)
    const int wc = w & 3;            // 0..3  (64-col block)
    const int srow = lane >> 3;      // 0..7
    const int sgrp = lane & 7;       // 0..7

    f32x4 acc[2][4] = {};

    auto stage = [&](int kt, int b) {
        int k0 = kt * BK;
        const unsigned short* As; int astr, ac0;
        if (k0 < TROW) { As = Tb; astr = TROW; ac0 = k0; }
        else           { As = Xb; astr = DIM;  ac0 = k0 - TROW; }
        int scol = (sgrp ^ srow) << 3;
        {   // A: 64 rows, 1 load/thread
            int rt = w * 8 + srow;
            int gr = m0 + rt; if (gr > N_NODES - 1) gr = N_NODES - 1;
            gload_lds16(As + (size_t)gr * astr + ac0 + scol, &At[b][(w * 8) * BK]);
        }
#pragma unroll
        for (int is = 0; is < 4; ++is) {   // B: 256 rows, 4 loads/thread
            int rt = w * 32 + is * 8 + srow;
            gload_lds16(W2 + (size_t)rt * K2 + k0 + scol, &Bt[b][(w * 32 + is * 8) * BK]);
        }
    };

    stage(0, 0);
    __syncthreads();    // drains vmcnt(0)

    for (int kt = 0; kt < NT; ++kt) {
        int cb = kt & 1;
        if (kt + 1 < NT) stage(kt + 1, cb ^ 1);   // prefetch overlaps compute below
#pragma unroll
        for (int kk = 0; kk < BK; kk += 32) {
            const int gg = (kk >> 3) + (lane >> 4);
            s16x8 af[2], bfr[4];
#pragma unroll
            for (int m = 0; m < 2; ++m) {
                int r = wr * 32 + m * 16 + (lane & 15);
                af[m] = *reinterpret_cast<const s16x8*>(&At[cb][r * BK + ((gg ^ (r & 7)) << 3)]);
            }
#pragma unroll
            for (int n = 0; n < 4; ++n) {
                int r = wc * 64 + n * 16 + (lane & 15);
                bfr[n] = *reinterpret_cast<const s16x8*>(&Bt[cb][r * BK + ((gg ^ (r & 7)) << 3)]);
            }
#pragma unroll
            for (int m = 0; m < 2; ++m)
#pragma unroll
                for (int n = 0; n < 4; ++n)
                    acc[m][n] = __builtin_amdgcn_mfma_f32_16x16x32_bf16(af[m], bfr[n], acc[m][n], 0, 0, 0);
        }
        __syncthreads();   // drains prefetch vmcnt + lds reads; buffers swap safely
    }

    // epilogue: out = acc + bias (f32 direct)
    float b4[4];
#pragma unroll
    for (int n = 0; n < 4; ++n) b4[n] = bias[wc * 64 + n * 16 + (lane & 15)];
#pragma unroll
    for (int m = 0; m < 2; ++m) {
        int rbase = m0 + wr * 32 + m * 16 + ((lane >> 4) * 4);
#pragma unroll
        for (int j = 0; j < 4; ++j) {
            int row = rbase + j;
            if (row < N_NODES) {
#pragma unroll
                for (int n = 0; n < 4; ++n) {
                    int col = wc * 64 + n * 16 + (lane & 15);
                    out[(size_t)row * DIM + col] = acc[m][n][j] + b4[n];
                }
            }
        }
    }
}

// ---------------------------------------------------------------------------
extern "C" void kernel_launch(void* const* d_in, const int* in_sizes, int n_in,
                              void* d_out, int out_size, void* d_ws, size_t ws_size,
                              hipStream_t stream) {
    const float* x      = (const float*)d_in[0];
    const int*   src    = (const int*)d_in[1];
    const int*   dst    = (const int*)d_in[2];
    const int*   etypes = (const int*)d_in[3];
    const float* basis  = (const float*)d_in[4];
    const float* comp   = (const float*)d_in[5];
    const float* loopw  = (const float*)d_in[6];
    const float* bias   = (const float*)d_in[7];
    float* out = (float*)d_out;

    char* p = (char*)d_ws;
    unsigned short* W2 = (unsigned short*)p;            p += (size_t)DIM * K2 * 2;          // 0.66 MB
    unsigned short* Xb = (unsigned short*)p;            p += (size_t)N_NODES * DIM * 2;     // 10.24 MB
    unsigned short* T  = (unsigned short*)p;            p += (size_t)N_NODES * TROW * 2;    // 40.96 MB
    int* cnt    = (int*)p;                              p += (size_t)N_NODES * 4;           // 80 KB
    int* bucket = (int*)p;                              p += (size_t)N_NODES * CAP * 4;     // 7.68 MB

    prep_all<<<PREPX_BLOCKS + DIM + NB, 256, 0, stream>>>(x, basis, loopw, Xb, W2, cnt);

    bucket_fill<<<(N_EDGES + 255) / 256, 256, 0, stream>>>(src, dst, etypes, cnt, bucket);

    gather_T<<<N_NODES / 4, 256, 0, stream>>>(cnt, bucket, Xb, comp, T);

    gemm_out<<<(N_NODES + BM - 1) / BM, 512, 0, stream>>>(T, Xb, W2, bias, out);
}